// Round 3
// baseline (121.128 us; speedup 1.0000x reference)
//
#include <hip/hip_runtime.h>
#include <math.h>

// Problem constants: IMG_SIZE=1024, B=64, G=128, A=3, N=1280, stride=8
#define NBOX     1280
#define BVAL     64
#define GVAL     128
#define NFLOAT   (BVAL * GVAL * GVAL * 15)   // 15,728,640 floats = 62.9 MB
#define NVEC     (NFLOAT / 4)                // 3,932,160 float4
#define SPAN_V4  2048                        // float4 per sweep block (32 KB span)
#define NSWEEP   (NVEC / SPAN_V4)            // 1920 exactly
#define NBLK     (NSWEEP + 1)                // + 1 box block

typedef float f32x4 __attribute__((ext_vector_type(4)));

__device__ __forceinline__ float softplus_f(float z) {
    return fmaxf(z, 0.f) + __logf(1.f + __expf(-fabsf(z)));
}

// blockIdx 0        : target build + dedup (fixed-trip, branch-free) + gather-adjust
// blockIdx 1..1920  : noobj sweep, register streaming with NON-TEMPORAL loads.
//                     R2 found: the harness's 256 MiB poison fill (42 µs, ≡1 mod 8
//                     in the dispatch stream) runs right before us and leaves the
//                     entire 256 MiB L3 dirty; allocating reads then pay an
//                     eviction-writeback per miss (timed yolo ~54 µs vs <42 µs in
//                     rocprof's cache-flushed replay). nt loads skip L2/L3
//                     allocation -> no eviction tax. y_pred has zero reuse, so
//                     bypassing the caches costs nothing.
// Partials via plain per-block stores — NO same-address atomics (prev session R3:
// serialized same-line atomicAdds cost ~42 µs).
__global__ void __launch_bounds__(256) yolo_loss_kernel(
    const float* __restrict__ yp,
    const float* __restrict__ gbox,
    const float* __restrict__ anch,
    const int*   __restrict__ bidx,
    float*       __restrict__ part)
{
    __shared__ int   skey[NBOX];   // box keys (block 0 only)
    __shared__ int   scnt[BVAL];   // per-batch counts; scnt[0] reused for maxseg
    __shared__ float swave[4];

    const int t = threadIdx.x;
    float acc = 0.f;

    if (blockIdx.x == 0) {
        if (t < BVAL) scnt[t] = 0;
        __syncthreads();

        // ---- phase 1: per-box key (kept in regs too) + batch histogram ----
        int mykey[5];
        #pragma unroll
        for (int k = 0; k < 5; k++) {
            int n = t + k * 256;                     // 5*256 == NBOX exactly
            float4 g = ((const float4*)gbox)[n];
            float gx = g.x * 0.125f;
            float gy = g.y * 0.125f;
            float gw = g.z * 0.125f;
            float gh = g.w * 0.125f;
            int gi = (int)gx, gj = (int)gy;
            int best = 0; float bestr = -1.f;
            #pragma unroll
            for (int a = 0; a < 3; a++) {
                float aw = anch[a * 2 + 0] * 0.125f;
                float ah = anch[a * 2 + 1] * 0.125f;
                float inter = fminf(aw, gw) * fminf(ah, gh);
                float uni   = aw * ah + gw * gh - inter;
                float r     = inter / uni;
                if (r > bestr) { bestr = r; best = a; }   // first-wins ties, like argmax
            }
            int b = bidx[n];
            int key = ((b * 3 + best) * 128 + gj) * 128 + gi;
            skey[n]  = key;
            mykey[k] = key;
            atomicAdd(&scnt[b], 1);                  // LDS atomic — cheap
        }
        __syncthreads();

        // ---- maxseg = max boxes in any batch (bound on duplicate-pair distance) ----
        if (t < 64) {
            int v = scnt[t];
            #pragma unroll
            for (int off = 32; off > 0; off >>= 1) v = max(v, __shfl_down(v, off, 64));
            if (t == 0) scnt[0] = v;
        }
        __syncthreads();
        const int maxseg = scnt[0];

        // ---- phase 2: dedup, last-write-wins; fixed trip count, branch-free ----
        bool win[5];
        #pragma unroll
        for (int k = 0; k < 5; k++) win[k] = true;
        for (int d = 1; d <= maxseg; d++) {
            #pragma unroll
            for (int k = 0; k < 5; k++) {
                int m2 = t + k * 256 + d;
                int mc = m2 < NBOX ? m2 : NBOX - 1;       // clamp (guard result below)
                int other = skey[mc];
                if (m2 < NBOX && other == mykey[k]) win[k] = false;
            }
        }

        // ---- phase 3: winners recompute targets + gather pred + accumulate ----
        #pragma unroll
        for (int k = 0; k < 5; k++) {
            if (!win[k]) continue;
            int n = t + k * 256;
            float4 g = ((const float4*)gbox)[n];
            float gx = g.x * 0.125f;
            float gy = g.y * 0.125f;
            float gw = g.z * 0.125f;
            float gh = g.w * 0.125f;
            int gi = (int)gx, gj = (int)gy;
            int best = 0; float bestr = -1.f, baw = 1.f, bah = 1.f;
            #pragma unroll
            for (int a = 0; a < 3; a++) {
                float aw = anch[a * 2 + 0] * 0.125f;
                float ah = anch[a * 2 + 1] * 0.125f;
                float inter = fminf(aw, gw) * fminf(ah, gh);
                float uni   = aw * ah + gw * gh - inter;
                float r     = inter / uni;
                if (r > bestr) { bestr = r; best = a; baw = aw; bah = ah; }
            }
            float tx = gx - (float)gi;
            float ty = gy - (float)gj;
            float tw = __logf(gw / baw);
            float th = __logf(gh / bah);
            int b = bidx[n];
            long base = ((((long)b * GVAL + gj) * GVAL) + gi) * 15 + best * 5;
            float conf = yp[base + 0];
            float px = 1.f / (1.f + __expf(-yp[base + 1]));
            float py = 1.f / (1.f + __expf(-yp[base + 2]));
            float pw = yp[base + 3];
            float ph = yp[base + 4];
            float dx = px - tx, dy = py - ty, dw = pw - tw, dh = ph - th;
            float lp = __logf(1.f + __expf(-fabsf(conf)));
            float sp_pos = fmaxf( conf, 0.f) + lp;   // softplus(conf)
            float sp_neg = fmaxf(-conf, 0.f) + lp;   // softplus(-conf)
            acc += 5.f * (dx * dx + dy * dy + dw * dw + dh * dh)
                 + sp_neg - 0.5f * sp_pos;           // obj minus over-counted noobj
        }
    } else {
        // ---- noobj sweep: 0.5 * sum softplus(words ≡ 0 mod 5) ----
        // Pure streaming: 8 coalesced NON-TEMPORAL float4 loads into registers;
        // exactly one conf per float4 at component j = m % 5 (skip when j == 4).
        // k-step is 256 ≡ 1 (mod 5) so j cycles by +1 per k — one add+wrap.
        const f32x4* src = (const f32x4*)yp + (long)(blockIdx.x - 1) * SPAN_V4;
        f32x4 v[8];
        #pragma unroll
        for (int k = 0; k < 8; k++) v[k] = __builtin_nontemporal_load(&src[t + k * 256]);

        int j = ((blockIdx.x - 1) * SPAN_V4 + t) % 5;
        float lacc = 0.f;
        #pragma unroll
        for (int k = 0; k < 8; k++) {
            float c  = (j == 0) ? v[k].x
                     : (j == 1) ? v[k].y
                     : (j == 2) ? v[k].z
                     :            v[k].w;
            float sp = softplus_f(c);
            lacc += (j < 4) ? sp : 0.f;              // j==4: float4 holds no conf
            j = (j == 4) ? 0 : j + 1;
        }
        acc = 0.5f * lacc;
    }

    // ---- block reduction: wave shuffle -> LDS -> ONE PLAIN STORE per block ----
    #pragma unroll
    for (int off = 32; off > 0; off >>= 1) acc += __shfl_down(acc, off, 64);
    int lane = t & 63, wid = t >> 6;
    if (lane == 0) swave[wid] = acc;
    __syncthreads();
    if (t == 0) part[blockIdx.x] = swave[0] + swave[1] + swave[2] + swave[3];
}

// Single-block final reduce of the 1921 partials; writes out[0] directly
// (plain store overwrites the 0xAA poison — no memset dispatch needed).
__global__ void __launch_bounds__(256) final_reduce_kernel(
    const float* __restrict__ part, float* __restrict__ out)
{
    __shared__ float swave[4];
    const int t = threadIdx.x;
    float acc = 0.f;
    for (int i = t; i < NBLK; i += 256) acc += part[i];
    #pragma unroll
    for (int off = 32; off > 0; off >>= 1) acc += __shfl_down(acc, off, 64);
    int lane = t & 63, wid = t >> 6;
    if (lane == 0) swave[wid] = acc;
    __syncthreads();
    if (t == 0) out[0] = swave[0] + swave[1] + swave[2] + swave[3];
}

extern "C" void kernel_launch(void* const* d_in, const int* in_sizes, int n_in,
                              void* d_out, int out_size, void* d_ws, size_t ws_size,
                              hipStream_t stream) {
    const float* yp   = (const float*)d_in[0];   // y_pred (B,G,G,15) fp32
    const float* gbox = (const float*)d_in[1];   // ground_bboxes (N,4) fp32
    const float* anch = (const float*)d_in[2];   // anchors (3,2) fp32
    const int*   bidx = (const int*)d_in[3];     // batch_idx (N,) int32
    float* part = (float*)d_ws;                  // NBLK partials (7684 B)
    float* out  = (float*)d_out;

    yolo_loss_kernel<<<dim3(NBLK), dim3(256), 0, stream>>>(yp, gbox, anch, bidx, part);
    final_reduce_kernel<<<dim3(1), dim3(256), 0, stream>>>(part, out);
}

// Round 4
// 110.473 us; speedup vs baseline: 1.0965x; 1.0965x over previous
//
#include <hip/hip_runtime.h>
#include <math.h>

// Problem constants: IMG_SIZE=1024, B=64, G=128, A=3, N=1280, stride=8
#define NBOX     1280
#define BVAL     64
#define GVAL     128
#define NFLOAT   (BVAL * GVAL * GVAL * 15)   // 15,728,640 floats = 62.9 MB
#define NVEC     (NFLOAT / 4)                // 3,932,160 float4
#define SPAN_V4  4096                        // float4 per sweep block (64 KB span)
#define NSWEEP   (NVEC / SPAN_V4)            // 960 exactly
#define NBLK     (NSWEEP + 1)                // + 1 box block

__device__ __forceinline__ float softplus_f(float z) {
    return fmaxf(z, 0.f) + __logf(1.f + __expf(-fabsf(z)));
}

// blockIdx 0       : target build + dedup (fixed-trip, branch-free) + gather-adjust
// blockIdx 1..960  : noobj sweep, SINGLE-GENERATION register streaming.
//                    R3 post-mortem: nt loads regressed +8 µs — they killed the
//                    inter-iteration L3 residency of y_pred (R0 FETCH=30.8 MB of
//                    63 MB read => half served from L3). Regular allocating loads
//                    restored.
//                    R4 change: 961 blocks total (~3.75/CU) so EVERY block is
//                    co-resident from t=0 — no block churn, no per-generation
//                    memory-pipe drain (occupancy was stuck at 8-14% with 1921
//                    short blocks). Each thread issues 16 float4 loads up front
//                    (64 KB/block span), then folds. Conf logits are every 5th
//                    word; float4 m holds one conf at component j = m % 5 (none
//                    when j==4); k-step 256 ≡ 1 (mod 5) so j advances by +1.
// Partials via plain per-block stores — NO same-address atomics.
__global__ void __launch_bounds__(256) yolo_loss_kernel(
    const float* __restrict__ yp,
    const float* __restrict__ gbox,
    const float* __restrict__ anch,
    const int*   __restrict__ bidx,
    float*       __restrict__ part)
{
    __shared__ int   skey[NBOX];   // box keys (block 0 only)
    __shared__ int   scnt[BVAL];   // per-batch counts; scnt[0] reused for maxseg
    __shared__ float swave[4];

    const int t = threadIdx.x;
    float acc = 0.f;

    if (blockIdx.x == 0) {
        if (t < BVAL) scnt[t] = 0;
        __syncthreads();

        // ---- phase 1: per-box key (kept in regs too) + batch histogram ----
        int mykey[5];
        #pragma unroll
        for (int k = 0; k < 5; k++) {
            int n = t + k * 256;                     // 5*256 == NBOX exactly
            float4 g = ((const float4*)gbox)[n];
            float gx = g.x * 0.125f;
            float gy = g.y * 0.125f;
            float gw = g.z * 0.125f;
            float gh = g.w * 0.125f;
            int gi = (int)gx, gj = (int)gy;
            int best = 0; float bestr = -1.f;
            #pragma unroll
            for (int a = 0; a < 3; a++) {
                float aw = anch[a * 2 + 0] * 0.125f;
                float ah = anch[a * 2 + 1] * 0.125f;
                float inter = fminf(aw, gw) * fminf(ah, gh);
                float uni   = aw * ah + gw * gh - inter;
                float r     = inter / uni;
                if (r > bestr) { bestr = r; best = a; }   // first-wins ties, like argmax
            }
            int b = bidx[n];
            int key = ((b * 3 + best) * 128 + gj) * 128 + gi;
            skey[n]  = key;
            mykey[k] = key;
            atomicAdd(&scnt[b], 1);                  // LDS atomic — cheap
        }
        __syncthreads();

        // ---- maxseg = max boxes in any batch (bound on duplicate-pair distance) ----
        if (t < 64) {
            int v = scnt[t];
            #pragma unroll
            for (int off = 32; off > 0; off >>= 1) v = max(v, __shfl_down(v, off, 64));
            if (t == 0) scnt[0] = v;
        }
        __syncthreads();
        const int maxseg = scnt[0];

        // ---- phase 2: dedup, last-write-wins; fixed trip count, branch-free ----
        bool win[5];
        #pragma unroll
        for (int k = 0; k < 5; k++) win[k] = true;
        for (int d = 1; d <= maxseg; d++) {
            #pragma unroll
            for (int k = 0; k < 5; k++) {
                int m2 = t + k * 256 + d;
                int mc = m2 < NBOX ? m2 : NBOX - 1;       // clamp (guard result below)
                int other = skey[mc];
                if (m2 < NBOX && other == mykey[k]) win[k] = false;
            }
        }

        // ---- phase 3: winners recompute targets + gather pred + accumulate ----
        #pragma unroll
        for (int k = 0; k < 5; k++) {
            if (!win[k]) continue;
            int n = t + k * 256;
            float4 g = ((const float4*)gbox)[n];
            float gx = g.x * 0.125f;
            float gy = g.y * 0.125f;
            float gw = g.z * 0.125f;
            float gh = g.w * 0.125f;
            int gi = (int)gx, gj = (int)gy;
            int best = 0; float bestr = -1.f, baw = 1.f, bah = 1.f;
            #pragma unroll
            for (int a = 0; a < 3; a++) {
                float aw = anch[a * 2 + 0] * 0.125f;
                float ah = anch[a * 2 + 1] * 0.125f;
                float inter = fminf(aw, gw) * fminf(ah, gh);
                float uni   = aw * ah + gw * gh - inter;
                float r     = inter / uni;
                if (r > bestr) { bestr = r; best = a; baw = aw; bah = ah; }
            }
            float tx = gx - (float)gi;
            float ty = gy - (float)gj;
            float tw = __logf(gw / baw);
            float th = __logf(gh / bah);
            int b = bidx[n];
            long base = ((((long)b * GVAL + gj) * GVAL) + gi) * 15 + best * 5;
            float conf = yp[base + 0];
            float px = 1.f / (1.f + __expf(-yp[base + 1]));
            float py = 1.f / (1.f + __expf(-yp[base + 2]));
            float pw = yp[base + 3];
            float ph = yp[base + 4];
            float dx = px - tx, dy = py - ty, dw = pw - tw, dh = ph - th;
            float lp = __logf(1.f + __expf(-fabsf(conf)));
            float sp_pos = fmaxf( conf, 0.f) + lp;   // softplus(conf)
            float sp_neg = fmaxf(-conf, 0.f) + lp;   // softplus(-conf)
            acc += 5.f * (dx * dx + dy * dy + dw * dw + dh * dh)
                 + sp_neg - 0.5f * sp_pos;           // obj minus over-counted noobj
        }
    } else {
        // ---- noobj sweep: 0.5 * sum softplus(words ≡ 0 mod 5) ----
        // 16 coalesced float4 loads issued up front (all in flight), then fold.
        const float4* src = (const float4*)yp + (long)(blockIdx.x - 1) * SPAN_V4;
        float4 v[16];
        #pragma unroll
        for (int k = 0; k < 16; k++) v[k] = src[t + k * 256];

        int j = ((blockIdx.x - 1) * SPAN_V4 + t) % 5;
        float lacc = 0.f;
        #pragma unroll
        for (int k = 0; k < 16; k++) {
            float c  = (j == 0) ? v[k].x
                     : (j == 1) ? v[k].y
                     : (j == 2) ? v[k].z
                     :            v[k].w;
            float sp = softplus_f(c);
            lacc += (j < 4) ? sp : 0.f;              // j==4: float4 holds no conf
            j = (j == 4) ? 0 : j + 1;
        }
        acc = 0.5f * lacc;
    }

    // ---- block reduction: wave shuffle -> LDS -> ONE PLAIN STORE per block ----
    #pragma unroll
    for (int off = 32; off > 0; off >>= 1) acc += __shfl_down(acc, off, 64);
    int lane = t & 63, wid = t >> 6;
    if (lane == 0) swave[wid] = acc;
    __syncthreads();
    if (t == 0) part[blockIdx.x] = swave[0] + swave[1] + swave[2] + swave[3];
}

// Single-block final reduce of the 961 partials; writes out[0] directly
// (plain store overwrites the 0xAA poison — no memset dispatch needed).
__global__ void __launch_bounds__(256) final_reduce_kernel(
    const float* __restrict__ part, float* __restrict__ out)
{
    __shared__ float swave[4];
    const int t = threadIdx.x;
    float acc = 0.f;
    for (int i = t; i < NBLK; i += 256) acc += part[i];
    #pragma unroll
    for (int off = 32; off > 0; off >>= 1) acc += __shfl_down(acc, off, 64);
    int lane = t & 63, wid = t >> 6;
    if (lane == 0) swave[wid] = acc;
    __syncthreads();
    if (t == 0) out[0] = swave[0] + swave[1] + swave[2] + swave[3];
}

extern "C" void kernel_launch(void* const* d_in, const int* in_sizes, int n_in,
                              void* d_out, int out_size, void* d_ws, size_t ws_size,
                              hipStream_t stream) {
    const float* yp   = (const float*)d_in[0];   // y_pred (B,G,G,15) fp32
    const float* gbox = (const float*)d_in[1];   // ground_bboxes (N,4) fp32
    const float* anch = (const float*)d_in[2];   // anchors (3,2) fp32
    const int*   bidx = (const int*)d_in[3];     // batch_idx (N,) int32
    float* part = (float*)d_ws;                  // NBLK partials (3844 B)
    float* out  = (float*)d_out;

    yolo_loss_kernel<<<dim3(NBLK), dim3(256), 0, stream>>>(yp, gbox, anch, bidx, part);
    final_reduce_kernel<<<dim3(1), dim3(256), 0, stream>>>(part, out);
}